// Round 10
// baseline (700.345 us; speedup 1.0000x reference)
//
#include <hip/hip_runtime.h>

typedef __attribute__((ext_vector_type(4))) float f32x4;
typedef __attribute__((ext_vector_type(8))) __bf16 bf16x8;

__device__ __forceinline__ unsigned short f2bf(float f) {
    return __builtin_bit_cast(unsigned short, (__bf16)f);
}
__device__ __forceinline__ float bf2f(unsigned short u) {
    return __builtin_bit_cast(float, (unsigned)u << 16);
}

__device__ __forceinline__ void gload16(const void* g, void* l) {
    __builtin_amdgcn_global_load_lds(
        (const __attribute__((address_space(1))) void*)g,
        (__attribute__((address_space(3))) void*)l, 16, 0, 0);
}

// ---------------- fused prep: cvt x->bf16 | build WT | degree histogram ----------------
__global__ __launch_bounds__(256) void k_prep(
    const float* __restrict__ x, unsigned short* __restrict__ xb, long total, long totalPad,
    const float* __restrict__ Wg, const float* __restrict__ Wh, const float* __restrict__ Wl,
    unsigned short* __restrict__ wt,
    const int* __restrict__ dst, int E, int* __restrict__ deg,
    int nCvt, int nHist) {
    const int b = blockIdx.x;
    const int tid = threadIdx.x;
    if (b < nCvt) {
        long i = ((long)b * 256 + tid) * 4;
        if (i >= totalPad) return;
        if (i < total) {
            float4 v = *(const float4*)(x + i);
            ushort4 u;
            u.x = f2bf(v.x); u.y = f2bf(v.y); u.z = f2bf(v.z); u.w = f2bf(v.w);
            *(ushort4*)(xb + i) = u;
        } else {
            ushort4 u = {0, 0, 0, 0};
            *(ushort4*)(xb + i) = u;
        }
    } else if (b < nCvt + 768) {
        int t = (b - nCvt) * 256 + tid;   // t = nn*256 + k
        int nn = t >> 8, k = t & 255;
        const float* W = (nn < 256) ? Wg : (nn < 512) ? Wh : Wl;
        wt[t] = f2bf(W[k * 256 + (nn & 255)]);
    } else {
        int bb = b - nCvt - 768;
        for (int e = bb * 256 + tid; e < E; e += nHist * 256)
            atomicAdd(&deg[dst[e]], 1);
    }
}

// ---------------- fused GEMM: C(Mpad x 768) = Xbf16 @ [Wg|Wh|Wl] ----------------
// 64-row x 768-col blocks: one 32KB A-stage (single barrier) feeds the FULL
// 768-col output for those rows (6x amortization). 256 threads / 4 waves,
// each wave owns 32 cols per tn. tn-loop x6 is barrier-free; B read from the
// L2-hot 384KB panel. 32KB LDS -> 4-5 blocks/CU so staging drains overlap
// with other blocks' MFMA (implicit wave-level pipelining).
__global__ __launch_bounds__(256, 4) void k_gemm(
    const unsigned short* __restrict__ A,   // Mpad x 256 bf16
    const unsigned short* __restrict__ BT,  // 768 x 256 bf16 (row n, col k)
    unsigned short* __restrict__ xs, unsigned short* __restrict__ hb,
    unsigned short* __restrict__ xlb,
    const float* __restrict__ bh, const float* __restrict__ bl, int M, int nwg) {
    __shared__ char Asm[32768];   // 64 rows x 256 k bf16, fragment-linear
    const int bid = blockIdx.x;
    const int xcd = bid & 7, idx = bid >> 3;
    const int q = nwg >> 3, r = nwg & 7;
    const int tm = (xcd < r ? xcd * (q + 1) : r * (q + 1) + (xcd - r) * q) + idx;

    const int tid = threadIdx.x;
    const int lane = tid & 63;
    const int wave = tid >> 6;        // 0..3
    const int wn = wave * 32;
    const int fr = lane & 15;
    const int ko = (lane >> 4) * 8;

    // stage 64x256 A tile (32KB): cell c = s*256+tid at byte c*16.
    // decode: r=c&15, kc=(c>>4)&31, m16=c>>9; layout byte=(m16*512+kc*16+r)*16
#pragma unroll
    for (int s = 0; s < 8; ++s) {
        const int c = s * 256 + tid;
        const int rr = c & 15;
        const int kc = (c >> 4) & 31;
        const int m16 = c >> 9;       // 0..3
        const unsigned short* g = A + (size_t)(tm * 64 + m16 * 16 + rr) * 256 + kc * 8;
        gload16(g, Asm + (size_t)c * 16);
    }
    __syncthreads();   // only barrier; covered by other resident blocks

    const char* Ab = Asm + lane * 16;   // af[i] at + i*8192 + ks*1024

    for (int tn = 0; tn < 6; ++tn) {
        f32x4 acc[4][2] = {};
        const unsigned short* Bg = BT + (size_t)(tn * 128 + wn + fr) * 256 + ko;
#pragma unroll
        for (int ks = 0; ks < 8; ++ks) {
            bf16x8 bfr[2], af[4];
#pragma unroll
            for (int j = 0; j < 2; ++j)
                bfr[j] = *(const bf16x8*)(Bg + (size_t)j * 16 * 256 + ks * 32);
#pragma unroll
            for (int i = 0; i < 4; ++i)
                af[i] = *(const bf16x8*)(Ab + i * 8192 + ks * 1024);
#pragma unroll
            for (int i = 0; i < 4; ++i)
#pragma unroll
                for (int j = 0; j < 2; ++j)
                    acc[i][j] = __builtin_amdgcn_mfma_f32_16x16x32_bf16(af[i], bfr[j], acc[i][j], 0, 0, 0);
        }
        // epilogue for this tn
        const int ob = tn >> 1;   // 0:xs 1:hb(+bh,relu) 2:xlb(+bl)
        unsigned short* obuf = (ob == 0) ? xs : (ob == 1) ? hb : xlb;
        const float* bias = (ob == 1) ? bh : bl;
        const int rbase = tm * 64 + (lane >> 4) * 4;
#pragma unroll
        for (int i = 0; i < 4; ++i) {
#pragma unroll
            for (int j = 0; j < 2; ++j) {
                const int c0 = (tn & 1) * 128 + wn + j * 16 + fr;   // col in 0..255
                float bv = (ob == 0) ? 0.f : bias[c0];
#pragma unroll
                for (int q2 = 0; q2 < 4; ++q2) {
                    const int rg = rbase + i * 16 + q2;
                    if (rg < M) {
                        float v = acc[i][j][q2] + bv;
                        if (ob == 1) v = v > 0.f ? v : 0.f;
                        obuf[(size_t)rg * 256 + c0] = f2bf(v);
                    }
                }
            }
        }
    }
}

// ---------------- a_src/a_dst: per (node, head) 32-length dot (bf16 xs) ----------------
__global__ __launch_bounds__(256) void k_attn(const unsigned short* __restrict__ xs,
                                              const float* __restrict__ att_src,
                                              const float* __restrict__ att_dst,
                                              float* __restrict__ a_src,
                                              float* __restrict__ a_dst, int N) {
    int t = blockIdx.x * 256 + threadIdx.x;
    int n = t >> 3, hh = t & 7;
    if (n >= N) return;
    const ushort4* xp = (const ushort4*)(xs + (size_t)n * 256 + hh * 32);
    const float4* sp = (const float4*)(att_src + hh * 32);
    const float4* dp = (const float4*)(att_dst + hh * 32);
    float sa = 0.f, sd = 0.f;
#pragma unroll
    for (int q = 0; q < 8; ++q) {
        ushort4 u = xp[q];
        float4 s = sp[q], d = dp[q];
        float v0 = bf2f(u.x), v1 = bf2f(u.y), v2 = bf2f(u.z), v3 = bf2f(u.w);
        sa += v0 * s.x + v1 * s.y + v2 * s.z + v3 * s.w;
        sd += v0 * d.x + v1 * d.y + v2 * d.z + v3 * d.w;
    }
    a_src[t] = sa;
    a_dst[t] = sd;
}

// ---------------- scans (over degrees padded to multiple of 8) ----------------
__global__ __launch_bounds__(256) void k_scan1(const int* __restrict__ deg, int* __restrict__ offs,
                                               int* __restrict__ bsum, int Npad) {
    __shared__ int s[256];
    int t = threadIdx.x;
    int i = blockIdx.x * 256 + t;
    int v = (i < Npad) ? ((deg[i] + 7) & ~7) : 0;
    s[t] = v;
    __syncthreads();
#pragma unroll
    for (int off = 1; off < 256; off <<= 1) {
        int x = (t >= off) ? s[t - off] : 0;
        __syncthreads();
        s[t] += x;
        __syncthreads();
    }
    offs[i] = s[t] - v;
    if (t == 255) bsum[blockIdx.x] = s[255];
}

__global__ __launch_bounds__(512) void k_scan2(int* __restrict__ bsum, int nb) {
    __shared__ int s[512];
    int t = threadIdx.x;
    int v = (t < nb) ? bsum[t] : 0;
    s[t] = v;
    __syncthreads();
#pragma unroll
    for (int off = 1; off < 512; off <<= 1) {
        int x = (t >= off) ? s[t - off] : 0;
        __syncthreads();
        s[t] += x;
        __syncthreads();
    }
    if (t < nb) bsum[t] = s[t] - v;
}

__global__ __launch_bounds__(256) void k_scan3(int* __restrict__ offs, const int* __restrict__ bsum,
                                               int* __restrict__ cursor) {
    int i = blockIdx.x * 256 + threadIdx.x;
    int o = offs[i] + bsum[blockIdx.x];
    offs[i] = o;
    cursor[i] = o;
}

// ---------------- edge pass: CSR scatter + per-(edge,head) pv = exp(leaky(logit))*w ----------------
__global__ void k_edge(const int* __restrict__ ei, const float* __restrict__ ea, int E,
                       const float* __restrict__ a_src, const float* __restrict__ a_dst,
                       int* __restrict__ cursor, int* __restrict__ srcArr,
                       unsigned short* __restrict__ pvArr) {
    for (int e = blockIdx.x * blockDim.x + threadIdx.x; e < E; e += gridDim.x * blockDim.x) {
        const int s = ei[e];
        const int d = ei[(size_t)E + e];
        const float w = ea[e];
        const int pos = atomicAdd(&cursor[d], 1);
        const float4* As = (const float4*)(a_src + (size_t)s * 8);
        const float4* Ad = (const float4*)(a_dst + (size_t)d * 8);
        float4 s0 = As[0], s1 = As[1], d0 = Ad[0], d1 = Ad[1];
        float a[8] = {s0.x + d0.x, s0.y + d0.y, s0.z + d0.z, s0.w + d0.w,
                      s1.x + d1.x, s1.y + d1.y, s1.z + d1.z, s1.w + d1.w};
        unsigned pk[4];
#pragma unroll
        for (int h = 0; h < 4; ++h) {
            float lo = a[2 * h], hi = a[2 * h + 1];
            lo = (lo > 0.f) ? lo : 0.2f * lo;
            hi = (hi > 0.f) ? hi : 0.2f * hi;
            unsigned short plo = f2bf(__expf(lo) * w);
            unsigned short phi = f2bf(__expf(hi) * w);
            pk[h] = (unsigned)plo | ((unsigned)phi << 16);
        }
        srcArr[pos] = s;
        uint4 v = {pk[0], pk[1], pk[2], pk[3]};
        *(uint4*)(pvArr + (size_t)pos * 8) = v;
    }
}

// ---------------- aggregation + epilogue: one wave per dst node ----------------
// Branch-free 8-edge body over zero-padded CSR: 1 coalesced src load,
// 8 row gathers + 8 pv direct loads issued together, then 8 FMA blocks.
__global__ __launch_bounds__(256) void k_agg(
    const int* __restrict__ offs, const int* __restrict__ deg,
    const int* __restrict__ srcArr, const unsigned short* __restrict__ pvArr,
    const unsigned short* __restrict__ xs, const unsigned short* __restrict__ hb,
    const unsigned short* __restrict__ xlb,
    const unsigned short* __restrict__ xbf, const float* __restrict__ ln_g,
    const float* __restrict__ ln_b,
    const float* __restrict__ beta, float* __restrict__ out, int N) {
    const int wave = threadIdx.x >> 6, lane = threadIdx.x & 63;
    const int n = blockIdx.x * 4 + wave;
    if (n >= N) return;
    const int start = offs[n];
    const int dpad = (deg[n] + 7) & ~7;
    const int head = lane >> 3;
    const int eSub = lane & 7;

    f32x4 acc = {0.f, 0.f, 0.f, 0.f};
    float dsum = 0.f;   // each lane sums its head's pv over all slots (pads contribute 0)

    const int* sp = srcArr + start;
    const unsigned short* pp = pvArr + (size_t)start * 8 + head;
    const char* xsb = (const char*)xs;
    const unsigned rowoff = (unsigned)lane * 8;

    for (int g = 0; g < dpad; g += 8) {
        const int sA = sp[g + eSub];
        ushort4 rows[8];
        float pvv[8];
#pragma unroll
        for (int e = 0; e < 8; ++e)
            rows[e] = *(const ushort4*)(xsb + (size_t)(unsigned)__shfl(sA, e) * 512 + rowoff);
#pragma unroll
        for (int e = 0; e < 8; ++e)
            pvv[e] = bf2f(pp[(size_t)(g + e) * 8]);
#pragma unroll
        for (int e = 0; e < 8; ++e) {
            const float p = pvv[e];
            dsum += p;
            acc[0] += p * bf2f(rows[e].x);
            acc[1] += p * bf2f(rows[e].y);
            acc[2] += p * bf2f(rows[e].z);
            acc[3] += p * bf2f(rows[e].w);
        }
    }
    const float inv = 1.f / (dsum + 1e-16f);

    // epilogue: xg = relu(msg + xl); t = h*xg; LN; beta-mix; + x (bf16 copy)
    const size_t base = (size_t)n * 256 + lane * 4;
    ushort4 xlu = *(const ushort4*)(xlb + base);
    ushort4 hu = *(const ushort4*)(hb + base);
    ushort4 xiu = *(const ushort4*)(xbf + base);
    f32x4 xg, t4;
    float s1 = 0.f, s2 = 0.f;
    const float xl0[4] = {bf2f(xlu.x), bf2f(xlu.y), bf2f(xlu.z), bf2f(xlu.w)};
    const float hv0[4] = {bf2f(hu.x), bf2f(hu.y), bf2f(hu.z), bf2f(hu.w)};
    const float xi0[4] = {bf2f(xiu.x), bf2f(xiu.y), bf2f(xiu.z), bf2f(xiu.w)};
#pragma unroll
    for (int q = 0; q < 4; ++q) {
        float gg = acc[q] * inv + xl0[q];
        gg = gg > 0.f ? gg : 0.f;
        xg[q] = gg;
        float t = hv0[q] * gg;
        t4[q] = t;
        s1 += t;
        s2 += t * t;
    }
#pragma unroll
    for (int off = 32; off; off >>= 1) {
        s1 += __shfl_xor(s1, off);
        s2 += __shfl_xor(s2, off);
    }
    const float mu = s1 * (1.f / 256.f);
    const float var = s2 * (1.f / 256.f) - mu * mu;
    const float rs = rsqrtf(var + 1e-5f);

    f32x4 g4 = *(const f32x4*)(ln_g + lane * 4);
    f32x4 b4 = *(const f32x4*)(ln_b + lane * 4);
    f32x4 be = *(const f32x4*)(beta + lane * 4);
    f32x4 o;
#pragma unroll
    for (int q = 0; q < 4; ++q) {
        float ln = (t4[q] - mu) * rs * g4[q] + b4[q];
        o[q] = (1.f - be[q]) * ln + be[q] * xg[q] + xi0[q];
    }
    *(f32x4*)(out + base) = o;
}

extern "C" void kernel_launch(void* const* d_in, const int* in_sizes, int n_in,
                              void* d_out, int out_size, void* d_ws, size_t ws_size,
                              hipStream_t stream) {
    const float* x = (const float*)d_in[0];
    const int* ei = (const int*)d_in[1];
    const float* ea = (const float*)d_in[2];
    const float* Wg = (const float*)d_in[3];
    const float* att_src = (const float*)d_in[4];
    const float* att_dst = (const float*)d_in[5];
    const float* Wh = (const float*)d_in[6];
    const float* bh = (const float*)d_in[7];
    const float* Wl = (const float*)d_in[8];
    const float* bl = (const float*)d_in[9];
    const float* ln_g = (const float*)d_in[10];
    const float* ln_b = (const float*)d_in[11];
    const float* beta = (const float*)d_in[12];
    float* out = (float*)d_out;

    const int DH = 256;
    const int N = in_sizes[0] / DH;      // 100000
    const int E = in_sizes[2];           // 1600000
    const int Mpad = ((N + 127) / 128) * 128;   // 100096 (multiple of 64)
    const int Npad = ((N + 255) / 256) * 256;   // 100096
    const int nscanb = Npad / 256;              // 391
    const int nwg = Mpad / 64;                  // 1564 row-tiles
    const int nCvt = Mpad / 4;                  // 25024
    const int nHist = 2048;
    const size_t Epad = (size_t)E + 8 * (size_t)N;   // padded CSR capacity

    char* w = (char*)d_ws;
    auto take = [&](size_t bytes) -> char* {
        char* p = w;
        w += (bytes + 255) & ~(size_t)255;
        return p;
    };
    unsigned short* xs = (unsigned short*)take((size_t)N * DH * 2);
    unsigned short* hb = (unsigned short*)take((size_t)N * DH * 2);
    unsigned short* xlb = (unsigned short*)take((size_t)N * DH * 2);
    float* a_src = (float*)take((size_t)N * 8 * 4);
    float* a_dst = (float*)take((size_t)N * 8 * 4);
    unsigned short* xbf = (unsigned short*)take((size_t)Mpad * DH * 2);
    unsigned short* wt = (unsigned short*)take((size_t)768 * 256 * 2);
    int* deg = (int*)take((size_t)Npad * 4);
    int* offs = (int*)take((size_t)Npad * 4);
    int* cursor = (int*)take((size_t)Npad * 4);
    int* bsum = (int*)take(512 * 4);
    int* srcArr = (int*)take(Epad * 4);
    unsigned short* pvArr = (unsigned short*)take(Epad * 8 * 2);

    hipMemsetAsync(deg, 0, (size_t)Npad * 4, stream);
    hipMemsetAsync(srcArr, 0, Epad * 4, stream);
    hipMemsetAsync(pvArr, 0, Epad * 8 * 2, stream);

    // fused prep: cvt + wt + hist
    k_prep<<<nCvt + 768 + nHist, 256, 0, stream>>>(x, xbf, (long)N * DH, (long)Mpad * DH,
                                                   Wg, Wh, Wl, wt, ei + E, E, deg, nCvt, nHist);

    // padded offsets
    k_scan1<<<nscanb, 256, 0, stream>>>(deg, offs, bsum, Npad);
    k_scan2<<<1, 512, 0, stream>>>(bsum, nscanb);
    k_scan3<<<nscanb, 256, 0, stream>>>(offs, bsum, cursor);

    // fused 3-way GEMM: 64-row x 768-col blocks, one A-stage amortized over 6 tn
    k_gemm<<<nwg, 256, 0, stream>>>(xbf, wt, xs, hb, xlb, bh, bl, N, nwg);

    // attention coefficients
    k_attn<<<(N * 8 + 255) / 256, 256, 0, stream>>>(xs, att_src, att_dst, a_src, a_dst, N);

    // edge pass: scatter + pv precompute
    k_edge<<<2048, 256, 0, stream>>>(ei, ea, E, a_src, a_dst, cursor, srcArr, pvArr);

    // aggregation + epilogue
    k_agg<<<(N + 3) / 4, 256, 0, stream>>>(offs, deg, srcArr, pvArr,
                                           xs, hb, xlb, xbf, ln_g, ln_b, beta, out, N);
}

// Round 11
// 601.460 us; speedup vs baseline: 1.1644x; 1.1644x over previous
//
#include <hip/hip_runtime.h>

typedef __attribute__((ext_vector_type(4))) float f32x4;
typedef __attribute__((ext_vector_type(8))) __bf16 bf16x8;

__device__ __forceinline__ unsigned short f2bf(float f) {
    return __builtin_bit_cast(unsigned short, (__bf16)f);
}
__device__ __forceinline__ float bf2f(unsigned short u) {
    return __builtin_bit_cast(float, (unsigned)u << 16);
}

__device__ __forceinline__ void gload16(const void* g, void* l) {
    __builtin_amdgcn_global_load_lds(
        (const __attribute__((address_space(1))) void*)g,
        (__attribute__((address_space(3))) void*)l, 16, 0, 0);
}

// ================= fused prep =================
// Section 1: A in fragment-CELL order. Tile rt = 64 rows x 256 k = 2048 cells x 16B.
//   cell c: m16=c>>9, kc=(c>>4)&31, r=c&15 -> value = x[rt*64+m16*16+r][kc*8 .. +7] (bf16)
// Section 2: B (W^T) in cell order. Panel tn2 = 64 cols x 256 k = 2048 cells.
//   cell c: cg=c>>9, kc=(c>>4)&31, cr=c&15 -> col = tn2*64+cg*16+cr, elems W[kc*8+e][col]
// Section 3: degree histogram.
__global__ __launch_bounds__(256) void k_prep(
    const float* __restrict__ x, unsigned short* __restrict__ xA, int N,
    const float* __restrict__ Wg, const float* __restrict__ Wh, const float* __restrict__ Wl,
    unsigned short* __restrict__ wtc,
    const int* __restrict__ dst, int E, int* __restrict__ deg,
    int nACell, int nWtc, int nHist) {
    const int b = blockIdx.x;
    const int tid = threadIdx.x;
    if (b < nACell) {
#pragma unroll
        for (int u = 0; u < 2; ++u) {
            const long ci = ((long)b * 256 + tid) * 2 + u;
            const int rt = (int)(ci >> 11);
            const int c = (int)(ci & 2047);
            const int m16 = c >> 9, kc = (c >> 4) & 31, rr = c & 15;
            const int row = rt * 64 + m16 * 16 + rr;
            ushort4 o0 = {0, 0, 0, 0}, o1 = {0, 0, 0, 0};
            if (row < N) {
                const float4* p = (const float4*)(x + (size_t)row * 256 + kc * 8);
                float4 v0 = p[0], v1 = p[1];
                o0.x = f2bf(v0.x); o0.y = f2bf(v0.y); o0.z = f2bf(v0.z); o0.w = f2bf(v0.w);
                o1.x = f2bf(v1.x); o1.y = f2bf(v1.y); o1.z = f2bf(v1.z); o1.w = f2bf(v1.w);
            }
            *(ushort4*)(xA + ci * 8) = o0;
            *(ushort4*)(xA + ci * 8 + 4) = o1;
        }
    } else if (b < nACell + nWtc) {
        const int gi = (b - nACell) * 256 + tid;   // 24576 cells total
        const int tn2 = gi >> 11;
        const int c = gi & 2047;
        const int cg = c >> 9, kc = (c >> 4) & 31, cr = c & 15;
        const int colg = tn2 * 64 + cg * 16 + cr;
        const float* W = (colg < 256) ? Wg : (colg < 512) ? Wh : Wl;
        const int c2 = colg & 255;
        ushort4 o0, o1;
        o0.x = f2bf(W[(kc * 8 + 0) * 256 + c2]);
        o0.y = f2bf(W[(kc * 8 + 1) * 256 + c2]);
        o0.z = f2bf(W[(kc * 8 + 2) * 256 + c2]);
        o0.w = f2bf(W[(kc * 8 + 3) * 256 + c2]);
        o1.x = f2bf(W[(kc * 8 + 4) * 256 + c2]);
        o1.y = f2bf(W[(kc * 8 + 5) * 256 + c2]);
        o1.z = f2bf(W[(kc * 8 + 6) * 256 + c2]);
        o1.w = f2bf(W[(kc * 8 + 7) * 256 + c2]);
        *(ushort4*)(wtc + (size_t)gi * 8) = o0;
        *(ushort4*)(wtc + (size_t)gi * 8 + 4) = o1;
    } else {
        const int bb = b - nACell - nWtc;
        for (int e = bb * 256 + tid; e < E; e += nHist * 256)
            atomicAdd(&deg[dst[e]], 1);
    }
}

// ================= fused GEMM =================
// Block = 64-col panel (tn2 of 12) x 16 row-tiles of 64 rows. B panel (32KB)
// staged ONCE and resident in LDS; A tile (32KB) staged per iter. All global
// accesses lane-contiguous (cell order); all LDS fragment reads base+lane*16
// (conflict-free). 64KB LDS -> 2 blocks/CU; store phase overlaps next A-stage.
__global__ __launch_bounds__(256) void k_gemm(
    const unsigned short* __restrict__ xA, const unsigned short* __restrict__ wtc,
    unsigned short* __restrict__ xs, unsigned short* __restrict__ hb,
    unsigned short* __restrict__ xlb,
    const float* __restrict__ bh, const float* __restrict__ bl, int M, int NIT) {
    __shared__ char Asm[32768];
    __shared__ char Bsm[32768];
    const int tn2 = blockIdx.x % 12;
    const int tmb = blockIdx.x / 12;
    const int tid = threadIdx.x;
    const int lane = tid & 63;
    const int wave = tid >> 6;
    const int wr = wave >> 1;        // row half: 0,1 (32 rows each)
    const int wc = wave & 1;         // col half: 0,1 (32 cols each)
    const int fr = lane & 15;

    // stage resident B panel (32KB) + first A tile (32KB)
    const long rt0 = (long)tmb * NIT;
#pragma unroll
    for (int s = 0; s < 8; ++s)
        gload16(wtc + ((size_t)tn2 * 2048 + s * 256 + tid) * 8, Bsm + (s * 256 + tid) * 16);
#pragma unroll
    for (int s = 0; s < 8; ++s)
        gload16(xA + (rt0 * 2048 + s * 256 + tid) * 8, Asm + (s * 256 + tid) * 16);
    __syncthreads();

    const int ob = tn2 >> 2;   // 0:xs 1:hb 2:xlb
    unsigned short* obuf = (ob == 0) ? xs : (ob == 1) ? hb : xlb;
    const float* bias = (ob == 1) ? bh : bl;
    const char* Ab = Asm + (wr * 2) * 8192 + lane * 16;
    const char* Bb = Bsm + (wc * 2) * 8192 + lane * 16;

    for (int it = 0; it < NIT; ++it) {
        f32x4 acc[2][2] = {};
#pragma unroll
        for (int ks = 0; ks < 8; ++ks) {
            bf16x8 af[2], bb2[2];
            af[0] = *(const bf16x8*)(Ab + ks * 1024);
            af[1] = *(const bf16x8*)(Ab + 8192 + ks * 1024);
            bb2[0] = *(const bf16x8*)(Bb + ks * 1024);
            bb2[1] = *(const bf16x8*)(Bb + 8192 + ks * 1024);
            acc[0][0] = __builtin_amdgcn_mfma_f32_16x16x32_bf16(af[0], bb2[0], acc[0][0], 0, 0, 0);
            acc[0][1] = __builtin_amdgcn_mfma_f32_16x16x32_bf16(af[0], bb2[1], acc[0][1], 0, 0, 0);
            acc[1][0] = __builtin_amdgcn_mfma_f32_16x16x32_bf16(af[1], bb2[0], acc[1][0], 0, 0, 0);
            acc[1][1] = __builtin_amdgcn_mfma_f32_16x16x32_bf16(af[1], bb2[1], acc[1][1], 0, 0, 0);
        }
        __syncthreads();             // done reading Asm
        if (it + 1 < NIT) {          // next A stage flies under the store phase
            const long rt = rt0 + it + 1;
#pragma unroll
            for (int s = 0; s < 8; ++s)
                gload16(xA + (rt * 2048 + s * 256 + tid) * 8, Asm + (s * 256 + tid) * 16);
        }
        // store this tile's results (overlaps staging)
        const int rbase = (int)((rt0 + it) * 64) + wr * 32 + (lane >> 4) * 4;
#pragma unroll
        for (int i = 0; i < 2; ++i) {
#pragma unroll
            for (int j = 0; j < 2; ++j) {
                const int c0 = (tn2 & 3) * 64 + wc * 32 + j * 16 + fr;
                const float bv = (ob == 0) ? 0.f : bias[c0];
#pragma unroll
                for (int q2 = 0; q2 < 4; ++q2) {
                    const int rg = rbase + i * 16 + q2;
                    if (rg < M) {
                        float v = acc[i][j][q2] + bv;
                        if (ob == 1) v = v > 0.f ? v : 0.f;
                        obuf[(size_t)rg * 256 + c0] = f2bf(v);
                    }
                }
            }
        }
        __syncthreads();             // staging drained; Asm holds next tile
    }
}

// ---------------- a_src/a_dst: per (node, head) 32-length dot (bf16 xs) ----------------
__global__ __launch_bounds__(256) void k_attn(const unsigned short* __restrict__ xs,
                                              const float* __restrict__ att_src,
                                              const float* __restrict__ att_dst,
                                              float* __restrict__ a_src,
                                              float* __restrict__ a_dst, int N) {
    int t = blockIdx.x * 256 + threadIdx.x;
    int n = t >> 3, hh = t & 7;
    if (n >= N) return;
    const ushort4* xp = (const ushort4*)(xs + (size_t)n * 256 + hh * 32);
    const float4* sp = (const float4*)(att_src + hh * 32);
    const float4* dp = (const float4*)(att_dst + hh * 32);
    float sa = 0.f, sd = 0.f;
#pragma unroll
    for (int q = 0; q < 8; ++q) {
        ushort4 u = xp[q];
        float4 s = sp[q], d = dp[q];
        float v0 = bf2f(u.x), v1 = bf2f(u.y), v2 = bf2f(u.z), v3 = bf2f(u.w);
        sa += v0 * s.x + v1 * s.y + v2 * s.z + v3 * s.w;
        sd += v0 * d.x + v1 * d.y + v2 * d.z + v3 * d.w;
    }
    a_src[t] = sa;
    a_dst[t] = sd;
}

// ---------------- scans (degrees padded to multiple of 8) ----------------
__global__ __launch_bounds__(256) void k_scan1(const int* __restrict__ deg, int* __restrict__ offs,
                                               int* __restrict__ bsum, int Npad) {
    __shared__ int s[256];
    int t = threadIdx.x;
    int i = blockIdx.x * 256 + t;
    int v = (i < Npad) ? ((deg[i] + 7) & ~7) : 0;
    s[t] = v;
    __syncthreads();
#pragma unroll
    for (int off = 1; off < 256; off <<= 1) {
        int x = (t >= off) ? s[t - off] : 0;
        __syncthreads();
        s[t] += x;
        __syncthreads();
    }
    offs[i] = s[t] - v;
    if (t == 255) bsum[blockIdx.x] = s[255];
}

__global__ __launch_bounds__(512) void k_scan2(int* __restrict__ bsum, int nb) {
    __shared__ int s[512];
    int t = threadIdx.x;
    int v = (t < nb) ? bsum[t] : 0;
    s[t] = v;
    __syncthreads();
#pragma unroll
    for (int off = 1; off < 512; off <<= 1) {
        int x = (t >= off) ? s[t - off] : 0;
        __syncthreads();
        s[t] += x;
        __syncthreads();
    }
    if (t < nb) bsum[t] = s[t] - v;
}

__global__ __launch_bounds__(256) void k_scan3(int* __restrict__ offs, const int* __restrict__ bsum,
                                               int* __restrict__ cursor) {
    int i = blockIdx.x * 256 + threadIdx.x;
    int o = offs[i] + bsum[blockIdx.x];
    offs[i] = o;
    cursor[i] = o;
}

// ---------------- edge pass: CSR scatter + per-(edge,head) pv ----------------
__global__ void k_edge(const int* __restrict__ ei, const float* __restrict__ ea, int E,
                       const float* __restrict__ a_src, const float* __restrict__ a_dst,
                       int* __restrict__ cursor, int* __restrict__ srcArr,
                       unsigned short* __restrict__ pvArr) {
    for (int e = blockIdx.x * blockDim.x + threadIdx.x; e < E; e += gridDim.x * blockDim.x) {
        const int s = ei[e];
        const int d = ei[(size_t)E + e];
        const float w = ea[e];
        const int pos = atomicAdd(&cursor[d], 1);
        const float4* As = (const float4*)(a_src + (size_t)s * 8);
        const float4* Ad = (const float4*)(a_dst + (size_t)d * 8);
        float4 s0 = As[0], s1 = As[1], d0 = Ad[0], d1 = Ad[1];
        float a[8] = {s0.x + d0.x, s0.y + d0.y, s0.z + d0.z, s0.w + d0.w,
                      s1.x + d1.x, s1.y + d1.y, s1.z + d1.z, s1.w + d1.w};
        unsigned pk[4];
#pragma unroll
        for (int h = 0; h < 4; ++h) {
            float lo = a[2 * h], hi = a[2 * h + 1];
            lo = (lo > 0.f) ? lo : 0.2f * lo;
            hi = (hi > 0.f) ? hi : 0.2f * hi;
            unsigned short plo = f2bf(__expf(lo) * w);
            unsigned short phi = f2bf(__expf(hi) * w);
            pk[h] = (unsigned)plo | ((unsigned)phi << 16);
        }
        srcArr[pos] = s;
        uint4 v = {pk[0], pk[1], pk[2], pk[3]};
        *(uint4*)(pvArr + (size_t)pos * 8) = v;
    }
}

// ---------------- aggregation + epilogue: one wave per dst node ----------------
__global__ __launch_bounds__(256) void k_agg(
    const int* __restrict__ offs, const int* __restrict__ deg,
    const int* __restrict__ srcArr, const unsigned short* __restrict__ pvArr,
    const unsigned short* __restrict__ xs, const unsigned short* __restrict__ hb,
    const unsigned short* __restrict__ xlb,
    const float* __restrict__ x, const float* __restrict__ ln_g,
    const float* __restrict__ ln_b,
    const float* __restrict__ beta, float* __restrict__ out, int N) {
    const int wave = threadIdx.x >> 6, lane = threadIdx.x & 63;
    const int n = blockIdx.x * 4 + wave;
    if (n >= N) return;
    const int start = offs[n];
    const int dpad = (deg[n] + 7) & ~7;
    const int head = lane >> 3;
    const int eSub = lane & 7;

    f32x4 acc = {0.f, 0.f, 0.f, 0.f};
    float dsum = 0.f;

    const int* sp = srcArr + start;
    const unsigned short* pp = pvArr + (size_t)start * 8 + head;
    const char* xsb = (const char*)xs;
    const unsigned rowoff = (unsigned)lane * 8;

    for (int g = 0; g < dpad; g += 8) {
        const int sA = sp[g + eSub];
        ushort4 rows[8];
        float pvv[8];
#pragma unroll
        for (int e = 0; e < 8; ++e)
            rows[e] = *(const ushort4*)(xsb + (size_t)(unsigned)__shfl(sA, e) * 512 + rowoff);
#pragma unroll
        for (int e = 0; e < 8; ++e)
            pvv[e] = bf2f(pp[(size_t)(g + e) * 8]);
#pragma unroll
        for (int e = 0; e < 8; ++e) {
            const float p = pvv[e];
            dsum += p;
            acc[0] += p * bf2f(rows[e].x);
            acc[1] += p * bf2f(rows[e].y);
            acc[2] += p * bf2f(rows[e].z);
            acc[3] += p * bf2f(rows[e].w);
        }
    }
    const float inv = 1.f / (dsum + 1e-16f);

    const size_t base = (size_t)n * 256 + lane * 4;
    ushort4 xlu = *(const ushort4*)(xlb + base);
    ushort4 hu = *(const ushort4*)(hb + base);
    f32x4 xg, t4;
    float s1 = 0.f, s2 = 0.f;
    const float xl0[4] = {bf2f(xlu.x), bf2f(xlu.y), bf2f(xlu.z), bf2f(xlu.w)};
    const float hv0[4] = {bf2f(hu.x), bf2f(hu.y), bf2f(hu.z), bf2f(hu.w)};
#pragma unroll
    for (int q = 0; q < 4; ++q) {
        float gg = acc[q] * inv + xl0[q];
        gg = gg > 0.f ? gg : 0.f;
        xg[q] = gg;
        float t = hv0[q] * gg;
        t4[q] = t;
        s1 += t;
        s2 += t * t;
    }
#pragma unroll
    for (int off = 32; off; off >>= 1) {
        s1 += __shfl_xor(s1, off);
        s2 += __shfl_xor(s2, off);
    }
    const float mu = s1 * (1.f / 256.f);
    const float var = s2 * (1.f / 256.f) - mu * mu;
    const float rs = rsqrtf(var + 1e-5f);

    f32x4 g4 = *(const f32x4*)(ln_g + lane * 4);
    f32x4 b4 = *(const f32x4*)(ln_b + lane * 4);
    f32x4 be = *(const f32x4*)(beta + lane * 4);
    f32x4 xin = *(const f32x4*)(x + base);
    f32x4 o;
#pragma unroll
    for (int q = 0; q < 4; ++q) {
        float ln = (t4[q] - mu) * rs * g4[q] + b4[q];
        o[q] = (1.f - be[q]) * ln + be[q] * xg[q] + xin[q];
    }
    *(f32x4*)(out + base) = o;
}

extern "C" void kernel_launch(void* const* d_in, const int* in_sizes, int n_in,
                              void* d_out, int out_size, void* d_ws, size_t ws_size,
                              hipStream_t stream) {
    const float* x = (const float*)d_in[0];
    const int* ei = (const int*)d_in[1];
    const float* ea = (const float*)d_in[2];
    const float* Wg = (const float*)d_in[3];
    const float* att_src = (const float*)d_in[4];
    const float* att_dst = (const float*)d_in[5];
    const float* Wh = (const float*)d_in[6];
    const float* bh = (const float*)d_in[7];
    const float* Wl = (const float*)d_in[8];
    const float* bl = (const float*)d_in[9];
    const float* ln_g = (const float*)d_in[10];
    const float* ln_b = (const float*)d_in[11];
    const float* beta = (const float*)d_in[12];
    float* out = (float*)d_out;

    const int DH = 256;
    const int N = in_sizes[0] / DH;      // 100000
    const int E = in_sizes[2];           // 1600000
    const int NIT = 16;
    const int nT0 = (N + 63) / 64;                       // 1563
    const int nTiles = ((nT0 + NIT - 1) / NIT) * NIT;    // 1568
    const int RB = nTiles / NIT;                         // 98
    const int Npad = ((N + 255) / 256) * 256;            // 100096
    const int nscanb = Npad / 256;                       // 391
    const int nACell = nTiles * 2048 / 512;              // 6272 blocks (2 cells/thr)
    const int nWtc = 96;
    const int nHist = 2048;
    const size_t Epad = (size_t)E + 8 * (size_t)N;

    char* w = (char*)d_ws;
    auto take = [&](size_t bytes) -> char* {
        char* p = w;
        w += (bytes + 255) & ~(size_t)255;
        return p;
    };
    unsigned short* xs = (unsigned short*)take((size_t)N * DH * 2);
    unsigned short* hb = (unsigned short*)take((size_t)N * DH * 2);
    unsigned short* xlb = (unsigned short*)take((size_t)N * DH * 2);
    float* a_src = (float*)take((size_t)N * 8 * 4);
    float* a_dst = (float*)take((size_t)N * 8 * 4);
    unsigned short* xA = (unsigned short*)take((size_t)nTiles * 32768);
    unsigned short* wtc = (unsigned short*)take((size_t)24576 * 16);
    int* deg = (int*)take((size_t)Npad * 4);
    int* offs = (int*)take((size_t)Npad * 4);
    int* cursor = (int*)take((size_t)Npad * 4);
    int* bsum = (int*)take(512 * 4);
    int* srcArr = (int*)take(Epad * 4);
    unsigned short* pvArr = (unsigned short*)take(Epad * 8 * 2);

    hipMemsetAsync(deg, 0, (size_t)Npad * 4, stream);
    hipMemsetAsync(srcArr, 0, Epad * 4, stream);
    hipMemsetAsync(pvArr, 0, Epad * 8 * 2, stream);

    // fused prep: A cells + W cells + hist
    k_prep<<<nACell + nWtc + nHist, 256, 0, stream>>>(x, xA, N, Wg, Wh, Wl, wtc,
                                                      ei + E, E, deg, nACell, nWtc, nHist);

    // padded offsets
    k_scan1<<<nscanb, 256, 0, stream>>>(deg, offs, bsum, Npad);
    k_scan2<<<1, 512, 0, stream>>>(bsum, nscanb);
    k_scan3<<<nscanb, 256, 0, stream>>>(offs, bsum, cursor);

    // fused 3-way GEMM: B-resident 64-col panels x 16 row-tiles, cell-order staging
    k_gemm<<<RB * 12, 256, 0, stream>>>(xA, wtc, xs, hb, xlb, bh, bl, N, NIT);

    // attention coefficients
    k_attn<<<(N * 8 + 255) / 256, 256, 0, stream>>>(xs, att_src, att_dst, a_src, a_dst, N);

    // edge pass: scatter + pv precompute
    k_edge<<<2048, 256, 0, stream>>>(ei, ea, E, a_src, a_dst, cursor, srcArr, pvArr);

    // aggregation + epilogue
    k_agg<<<(N + 3) / 4, 256, 0, stream>>>(offs, deg, srcArr, pvArr,
                                           xs, hb, xlb, x, ln_g, ln_b, beta, out, N);
}

// Round 12
// 577.384 us; speedup vs baseline: 1.2130x; 1.0417x over previous
//
#include <hip/hip_runtime.h>

typedef __attribute__((ext_vector_type(4))) float f32x4;
typedef __attribute__((ext_vector_type(8))) __bf16 bf16x8;

__device__ __forceinline__ unsigned short f2bf(float f) {
    return __builtin_bit_cast(unsigned short, (__bf16)f);
}
__device__ __forceinline__ float bf2f(unsigned short u) {
    return __builtin_bit_cast(float, (unsigned)u << 16);
}

__device__ __forceinline__ void gload16(const void* g, void* l) {
    __builtin_amdgcn_global_load_lds(
        (const __attribute__((address_space(1))) void*)g,
        (__attribute__((address_space(3))) void*)l, 16, 0, 0);
}

// ---------------- fused prep: cvt x->bf16 | build WT | degree histogram ----------------
__global__ __launch_bounds__(256) void k_prep(
    const float* __restrict__ x, unsigned short* __restrict__ xb, long total, long totalPad,
    const float* __restrict__ Wg, const float* __restrict__ Wh, const float* __restrict__ Wl,
    unsigned short* __restrict__ wt,
    const int* __restrict__ dst, int E, int* __restrict__ deg,
    int nCvt, int nHist) {
    const int b = blockIdx.x;
    const int tid = threadIdx.x;
    if (b < nCvt) {
        long i = ((long)b * 256 + tid) * 4;
        if (i >= totalPad) return;
        if (i < total) {
            float4 v = *(const float4*)(x + i);
            ushort4 u;
            u.x = f2bf(v.x); u.y = f2bf(v.y); u.z = f2bf(v.z); u.w = f2bf(v.w);
            *(ushort4*)(xb + i) = u;
        } else {
            ushort4 u = {0, 0, 0, 0};
            *(ushort4*)(xb + i) = u;
        }
    } else if (b < nCvt + 768) {
        int t = (b - nCvt) * 256 + tid;   // t = nn*256 + k
        int nn = t >> 8, k = t & 255;
        const float* W = (nn < 256) ? Wg : (nn < 512) ? Wh : Wl;
        wt[t] = f2bf(W[k * 256 + (nn & 255)]);
    } else {
        int bb = b - nCvt - 768;
        for (int e = bb * 256 + tid; e < E; e += nHist * 256)
            atomicAdd(&deg[dst[e]], 1);
    }
}

// ---------------- fused GEMM: C(Mpad x 768) = Xbf16 @ [Wg|Wh|Wl] ----------------
// R6 structure (128x128 tile, 4 waves, 4x4 acc, 2 barriers/ks) + slot-XOR
// swizzle (both sides): source slot permuted WITHIN its 64B segment (coalescing
// unchanged), fragment read XORs the same function of row -> 2-way bank
// aliasing (free, m136) instead of 8-way.
__global__ __launch_bounds__(256) void k_gemm(
    const unsigned short* __restrict__ A,   // Mpad x 256 bf16
    const unsigned short* __restrict__ BT,  // 768 x 256 bf16 (row n, col k)
    unsigned short* __restrict__ xs, unsigned short* __restrict__ hb,
    unsigned short* __restrict__ xlb,
    const float* __restrict__ bh, const float* __restrict__ bl, int M, int nwg) {
    __shared__ unsigned short Al[128 * 32];
    __shared__ unsigned short Bl[128 * 32];
    const int bid = blockIdx.x;
    const int xcd = bid & 7, idx = bid >> 3;
    const int q = nwg >> 3, r = nwg & 7;
    const int wg = (xcd < r ? xcd * (q + 1) : r * (q + 1) + (xcd - r) * q) + idx;
    const int tm = wg / 6, tn = wg % 6;

    const int tid = threadIdx.x;
    const int lane = tid & 63;
    const int wave = tid >> 6;
    const int wm = (wave >> 1) * 64, wn = (wave & 1) * 64;

    f32x4 acc[4][4] = {};

    // staging: thread t -> LDS byte t*16 (+s*4096); global row r0=t>>2,
    // SWIZZLED slot ((t&3)^((t>>3)&3)) within the row's 64B ks-chunk.
    const int r0 = tid >> 2;
    const int ceSw = ((tid & 3) ^ ((tid >> 3) & 3)) * 8;
    const unsigned short* Ag = A + (size_t)tm * 128 * 256 + (size_t)r0 * 256 + ceSw;
    const unsigned short* Bg = BT + (size_t)tn * 128 * 256 + (size_t)r0 * 256 + ceSw;

    const int fr = lane & 15;
    const int sSw = (((lane >> 4) ^ ((fr >> 1) & 3))) * 16;   // swizzled slot byte

    for (int ks = 0; ks < 8; ++ks) {
        const int k0 = ks * 32;
#pragma unroll
        for (int s = 0; s < 2; ++s) {
            gload16(Ag + (size_t)s * 64 * 256 + k0, (char*)Al + s * 4096 + wave * 1024);
            gload16(Bg + (size_t)s * 64 * 256 + k0, (char*)Bl + s * 4096 + wave * 1024);
        }
        __syncthreads();
        bf16x8 af[4], bfr[4];
#pragma unroll
        for (int i = 0; i < 4; ++i) {
            af[i]  = *(const bf16x8*)((const char*)Al + (wm + i * 16 + fr) * 64 + sSw);
            bfr[i] = *(const bf16x8*)((const char*)Bl + (wn + i * 16 + fr) * 64 + sSw);
        }
#pragma unroll
        for (int i = 0; i < 4; ++i)
#pragma unroll
            for (int j = 0; j < 4; ++j)
                acc[i][j] = __builtin_amdgcn_mfma_f32_16x16x32_bf16(af[i], bfr[j], acc[i][j], 0, 0, 0);
        __syncthreads();
    }

    const int colbase = tn * 128 + wn;
    const int rbase = tm * 128 + wm + (lane >> 4) * 4;
#pragma unroll
    for (int i = 0; i < 4; ++i) {
#pragma unroll
        for (int j = 0; j < 4; ++j) {
            const int cg = colbase + j * 16 + (lane & 15);
#pragma unroll
            for (int q2 = 0; q2 < 4; ++q2) {
                const int rg = rbase + i * 16 + q2;
                if (rg < M) {
                    float v = acc[i][j][q2];
                    if (cg < 256) {
                        xs[(size_t)rg * 256 + cg] = f2bf(v);
                    } else if (cg < 512) {
                        float t = v + bh[cg - 256];
                        hb[(size_t)rg * 256 + (cg - 256)] = f2bf(t > 0.f ? t : 0.f);
                    } else {
                        xlb[(size_t)rg * 256 + (cg - 512)] = f2bf(v + bl[cg - 512]);
                    }
                }
            }
        }
    }
}

// ---------------- a_src/a_dst: per (node, head) 32-length dot (bf16 xs) ----------------
__global__ __launch_bounds__(256) void k_attn(const unsigned short* __restrict__ xs,
                                              const float* __restrict__ att_src,
                                              const float* __restrict__ att_dst,
                                              float* __restrict__ a_src,
                                              float* __restrict__ a_dst, int N) {
    int t = blockIdx.x * 256 + threadIdx.x;
    int n = t >> 3, hh = t & 7;
    if (n >= N) return;
    const ushort4* xp = (const ushort4*)(xs + (size_t)n * 256 + hh * 32);
    const float4* sp = (const float4*)(att_src + hh * 32);
    const float4* dp = (const float4*)(att_dst + hh * 32);
    float sa = 0.f, sd = 0.f;
#pragma unroll
    for (int q = 0; q < 8; ++q) {
        ushort4 u = xp[q];
        float4 s = sp[q], d = dp[q];
        float v0 = bf2f(u.x), v1 = bf2f(u.y), v2 = bf2f(u.z), v3 = bf2f(u.w);
        sa += v0 * s.x + v1 * s.y + v2 * s.z + v3 * s.w;
        sd += v0 * d.x + v1 * d.y + v2 * d.z + v3 * d.w;
    }
    a_src[t] = sa;
    a_dst[t] = sd;
}

// ---------------- scans (degrees padded to multiple of 8) ----------------
__global__ __launch_bounds__(256) void k_scan1(const int* __restrict__ deg, int* __restrict__ offs,
                                               int* __restrict__ bsum, int Npad) {
    __shared__ int s[256];
    int t = threadIdx.x;
    int i = blockIdx.x * 256 + t;
    int v = (i < Npad) ? ((deg[i] + 7) & ~7) : 0;
    s[t] = v;
    __syncthreads();
#pragma unroll
    for (int off = 1; off < 256; off <<= 1) {
        int x = (t >= off) ? s[t - off] : 0;
        __syncthreads();
        s[t] += x;
        __syncthreads();
    }
    offs[i] = s[t] - v;
    if (t == 255) bsum[blockIdx.x] = s[255];
}

__global__ __launch_bounds__(512) void k_scan2(int* __restrict__ bsum, int nb) {
    __shared__ int s[512];
    int t = threadIdx.x;
    int v = (t < nb) ? bsum[t] : 0;
    s[t] = v;
    __syncthreads();
#pragma unroll
    for (int off = 1; off < 512; off <<= 1) {
        int x = (t >= off) ? s[t - off] : 0;
        __syncthreads();
        s[t] += x;
        __syncthreads();
    }
    if (t < nb) bsum[t] = s[t] - v;
}

__global__ __launch_bounds__(256) void k_scan3(int* __restrict__ offs, const int* __restrict__ bsum,
                                               int* __restrict__ cursor) {
    int i = blockIdx.x * 256 + threadIdx.x;
    int o = offs[i] + bsum[blockIdx.x];
    offs[i] = o;
    cursor[i] = o;
}

// ---------------- edge pass: CSR scatter + per-(edge,head) pv ----------------
__global__ void k_edge(const int* __restrict__ ei, const float* __restrict__ ea, int E,
                       const float* __restrict__ a_src, const float* __restrict__ a_dst,
                       int* __restrict__ cursor, int* __restrict__ srcArr,
                       unsigned short* __restrict__ pvArr) {
    for (int e = blockIdx.x * blockDim.x + threadIdx.x; e < E; e += gridDim.x * blockDim.x) {
        const int s = ei[e];
        const int d = ei[(size_t)E + e];
        const float w = ea[e];
        const int pos = atomicAdd(&cursor[d], 1);
        const float4* As = (const float4*)(a_src + (size_t)s * 8);
        const float4* Ad = (const float4*)(a_dst + (size_t)d * 8);
        float4 s0 = As[0], s1 = As[1], d0 = Ad[0], d1 = Ad[1];
        float a[8] = {s0.x + d0.x, s0.y + d0.y, s0.z + d0.z, s0.w + d0.w,
                      s1.x + d1.x, s1.y + d1.y, s1.z + d1.z, s1.w + d1.w};
        unsigned pk[4];
#pragma unroll
        for (int h = 0; h < 4; ++h) {
            float lo = a[2 * h], hi = a[2 * h + 1];
            lo = (lo > 0.f) ? lo : 0.2f * lo;
            hi = (hi > 0.f) ? hi : 0.2f * hi;
            unsigned short plo = f2bf(__expf(lo) * w);
            unsigned short phi = f2bf(__expf(hi) * w);
            pk[h] = (unsigned)plo | ((unsigned)phi << 16);
        }
        srcArr[pos] = s;
        uint4 v = {pk[0], pk[1], pk[2], pk[3]};
        *(uint4*)(pvArr + (size_t)pos * 8) = v;
    }
}

// ---------------- aggregation + epilogue: one wave per dst node ----------------
__global__ __launch_bounds__(256) void k_agg(
    const int* __restrict__ offs, const int* __restrict__ deg,
    const int* __restrict__ srcArr, const unsigned short* __restrict__ pvArr,
    const unsigned short* __restrict__ xs, const unsigned short* __restrict__ hb,
    const unsigned short* __restrict__ xlb,
    const float* __restrict__ x, const float* __restrict__ ln_g,
    const float* __restrict__ ln_b,
    const float* __restrict__ beta, float* __restrict__ out, int N) {
    const int wave = threadIdx.x >> 6, lane = threadIdx.x & 63;
    const int n = blockIdx.x * 4 + wave;
    if (n >= N) return;
    const int start = offs[n];
    const int dpad = (deg[n] + 7) & ~7;
    const int head = lane >> 3;
    const int eSub = lane & 7;

    f32x4 acc = {0.f, 0.f, 0.f, 0.f};
    float dsum = 0.f;

    const int* sp = srcArr + start;
    const unsigned short* pp = pvArr + (size_t)start * 8 + head;
    const char* xsb = (const char*)xs;
    const unsigned rowoff = (unsigned)lane * 8;

    for (int g = 0; g < dpad; g += 8) {
        const int sA = sp[g + eSub];
        ushort4 rows[8];
        float pvv[8];
#pragma unroll
        for (int e = 0; e < 8; ++e)
            rows[e] = *(const ushort4*)(xsb + (size_t)(unsigned)__shfl(sA, e) * 512 + rowoff);
#pragma unroll
        for (int e = 0; e < 8; ++e)
            pvv[e] = bf2f(pp[(size_t)(g + e) * 8]);
#pragma unroll
        for (int e = 0; e < 8; ++e) {
            const float p = pvv[e];
            dsum += p;
            acc[0] += p * bf2f(rows[e].x);
            acc[1] += p * bf2f(rows[e].y);
            acc[2] += p * bf2f(rows[e].z);
            acc[3] += p * bf2f(rows[e].w);
        }
    }
    const float inv = 1.f / (dsum + 1e-16f);

    const size_t base = (size_t)n * 256 + lane * 4;
    ushort4 xlu = *(const ushort4*)(xlb + base);
    ushort4 hu = *(const ushort4*)(hb + base);
    f32x4 xg, t4;
    float s1 = 0.f, s2 = 0.f;
    const float xl0[4] = {bf2f(xlu.x), bf2f(xlu.y), bf2f(xlu.z), bf2f(xlu.w)};
    const float hv0[4] = {bf2f(hu.x), bf2f(hu.y), bf2f(hu.z), bf2f(hu.w)};
#pragma unroll
    for (int q = 0; q < 4; ++q) {
        float gg = acc[q] * inv + xl0[q];
        gg = gg > 0.f ? gg : 0.f;
        xg[q] = gg;
        float t = hv0[q] * gg;
        t4[q] = t;
        s1 += t;
        s2 += t * t;
    }
#pragma unroll
    for (int off = 32; off; off >>= 1) {
        s1 += __shfl_xor(s1, off);
        s2 += __shfl_xor(s2, off);
    }
    const float mu = s1 * (1.f / 256.f);
    const float var = s2 * (1.f / 256.f) - mu * mu;
    const float rs = rsqrtf(var + 1e-5f);

    f32x4 g4 = *(const f32x4*)(ln_g + lane * 4);
    f32x4 b4 = *(const f32x4*)(ln_b + lane * 4);
    f32x4 be = *(const f32x4*)(beta + lane * 4);
    f32x4 xin = *(const f32x4*)(x + base);
    f32x4 o;
#pragma unroll
    for (int q = 0; q < 4; ++q) {
        float ln = (t4[q] - mu) * rs * g4[q] + b4[q];
        o[q] = (1.f - be[q]) * ln + be[q] * xg[q] + xin[q];
    }
    *(f32x4*)(out + base) = o;
}

extern "C" void kernel_launch(void* const* d_in, const int* in_sizes, int n_in,
                              void* d_out, int out_size, void* d_ws, size_t ws_size,
                              hipStream_t stream) {
    const float* x = (const float*)d_in[0];
    const int* ei = (const int*)d_in[1];
    const float* ea = (const float*)d_in[2];
    const float* Wg = (const float*)d_in[3];
    const float* att_src = (const float*)d_in[4];
    const float* att_dst = (const float*)d_in[5];
    const float* Wh = (const float*)d_in[6];
    const float* bh = (const float*)d_in[7];
    const float* Wl = (const float*)d_in[8];
    const float* bl = (const float*)d_in[9];
    const float* ln_g = (const float*)d_in[10];
    const float* ln_b = (const float*)d_in[11];
    const float* beta = (const float*)d_in[12];
    float* out = (float*)d_out;

    const int DH = 256;
    const int N = in_sizes[0] / DH;      // 100000
    const int E = in_sizes[2];           // 1600000
    const int Mpad = ((N + 127) / 128) * 128;   // 100096
    const int Npad = ((N + 255) / 256) * 256;   // 100096
    const int nscanb = Npad / 256;              // 391
    const int nwg = (Mpad / 128) * 6;           // 4692
    const int nCvt = Mpad / 4;                  // 25024
    const int nHist = 2048;
    const size_t Epad = (size_t)E + 8 * (size_t)N;

    char* w = (char*)d_ws;
    auto take = [&](size_t bytes) -> char* {
        char* p = w;
        w += (bytes + 255) & ~(size_t)255;
        return p;
    };
    unsigned short* xs = (unsigned short*)take((size_t)N * DH * 2);
    unsigned short* hb = (unsigned short*)take((size_t)N * DH * 2);
    unsigned short* xlb = (unsigned short*)take((size_t)N * DH * 2);
    float* a_src = (float*)take((size_t)N * 8 * 4);
    float* a_dst = (float*)take((size_t)N * 8 * 4);
    unsigned short* xbf = (unsigned short*)take((size_t)Mpad * DH * 2);
    unsigned short* wt = (unsigned short*)take((size_t)768 * 256 * 2);
    int* deg = (int*)take((size_t)Npad * 4);
    int* offs = (int*)take((size_t)Npad * 4);
    int* cursor = (int*)take((size_t)Npad * 4);
    int* bsum = (int*)take(512 * 4);
    int* srcArr = (int*)take(Epad * 4);
    unsigned short* pvArr = (unsigned short*)take(Epad * 8 * 2);

    hipMemsetAsync(deg, 0, (size_t)Npad * 4, stream);
    hipMemsetAsync(srcArr, 0, Epad * 4, stream);
    hipMemsetAsync(pvArr, 0, Epad * 8 * 2, stream);

    // fused prep: cvt + wt + hist
    k_prep<<<nCvt + 768 + nHist, 256, 0, stream>>>(x, xbf, (long)N * DH, (long)Mpad * DH,
                                                   Wg, Wh, Wl, wt, ei + E, E, deg, nCvt, nHist);

    // padded offsets
    k_scan1<<<nscanb, 256, 0, stream>>>(deg, offs, bsum, Npad);
    k_scan2<<<1, 512, 0, stream>>>(bsum, nscanb);
    k_scan3<<<nscanb, 256, 0, stream>>>(offs, bsum, cursor);

    // fused 3-way GEMM (R6 structure + slot-XOR swizzle)
    k_gemm<<<nwg, 256, 0, stream>>>(xbf, wt, xs, hb, xlb, bh, bl, N, nwg);

    // attention coefficients
    k_attn<<<(N * 8 + 255) / 256, 256, 0, stream>>>(xs, att_src, att_dst, a_src, a_dst, N);

    // edge pass: scatter + pv precompute
    k_edge<<<2048, 256, 0, stream>>>(ei, ea, E, a_src, a_dst, cursor, srcArr, pvArr);

    // aggregation + epilogue
    k_agg<<<(N + 3) / 4, 256, 0, stream>>>(offs, deg, srcArr, pvArr,
                                           xs, hb, xlb, x, ln_g, ln_b, beta, out, N);
}